// Round 1
// baseline (942.628 us; speedup 1.0000x reference)
//
#include <hip/hip_runtime.h>
#include <hip/hip_bf16.h>

#define NN 50000
#define NE 800000
#define NG 256
#define DIN 128
#define DH 512
#define DC 256   // conv channels
#define DL 128   // lin2 out

// ---------------- workspace layout (bytes) ----------------
#define H1_OFF   0UL                      // 50000*512*4 = 102,400,000
#define HW_OFF   102400000UL              // 50000*256*4 =  51,200,000
#define H2_OFF   153600000UL              // 50000*256*4 =  51,200,000
#define CNT_OFF  204800000UL              // 50000*4
#define FILL_OFF 205000000UL              // 50000*4  (must follow CNT: one memset)
#define DINV_OFF 205200000UL              // 50000*4
#define RP_OFF   205400000UL              // 50001*4
#define COL_OFF  205600064UL              // 800000*4 -> end ~208.8 MB

// ---------------- graph-structure kernels ----------------
__global__ void count_in(const int* __restrict__ dst, int* __restrict__ cnt) {
  int e = blockIdx.x * blockDim.x + threadIdx.x;
  if (e < NE) atomicAdd(&cnt[dst[e]], 1);
}

__global__ void compute_dinv(const int* __restrict__ cnt, float* __restrict__ dinv) {
  int i = blockIdx.x * blockDim.x + threadIdx.x;
  if (i < NN) dinv[i] = 1.0f / sqrtf((float)(cnt[i] + 1));   // +1 self-loop
}

// single-block exclusive scan of cnt[0..NN) -> rowptr; rowptr[NN] = total
__global__ __launch_bounds__(1024) void scan_rowptr(const int* __restrict__ cnt,
                                                    int* __restrict__ rowptr) {
  __shared__ int wsum[16];
  __shared__ int soff_s;
  const int lane = threadIdx.x & 63, wid = threadIdx.x >> 6;
  if (threadIdx.x == 0) soff_s = 0;
  __syncthreads();
  for (int base = 0; base < NN; base += 1024) {
    int idx = base + threadIdx.x;
    int v = (idx < NN) ? cnt[idx] : 0;
    int incl = v;
    #pragma unroll
    for (int s = 1; s < 64; s <<= 1) {
      int t = __shfl_up(incl, s, 64);
      if (lane >= s) incl += t;
    }
    if (lane == 63) wsum[wid] = incl;
    __syncthreads();
    int woff = 0;
    for (int w = 0; w < wid; ++w) woff += wsum[w];
    int soff = soff_s;
    if (idx < NN) rowptr[idx] = soff + woff + incl - v;
    __syncthreads();
    if (threadIdx.x == 1023) soff_s += woff + incl;  // running total
    __syncthreads();
  }
  if (threadIdx.x == 0) rowptr[NN] = soff_s;
}

__global__ void fill_csr(const int* __restrict__ src, const int* __restrict__ dst,
                         const int* __restrict__ rowptr, int* __restrict__ fill,
                         int* __restrict__ colidx) {
  int e = blockIdx.x * blockDim.x + threadIdx.x;
  if (e < NE) {
    int d = dst[e];
    int pos = rowptr[d] + atomicAdd(&fill[d], 1);
    colidx[pos] = src[e];
  }
}

// ---------------- fp32 tiled GEMM: C = relu?(A[M,K] @ B[K,N] (+bias)) ----------------
// 64x64 tile, 256 threads, 4x4 microtile, K-step 16. N must be a multiple of 64,
// K a multiple of 16 (true here: N in {512,256}, K in {128,512,256}).
template<int DO_RELU, int HAS_BIAS>
__global__ __launch_bounds__(256) void gemm_f32(
    const float* __restrict__ A, const float* __restrict__ B,
    const float* __restrict__ bias, float* __restrict__ C,
    int M, int K, int N)
{
  __shared__ float As[16][68];   // pad 64->68: spreads writes across banks
  __shared__ float Bs[16][68];
  const int bm = blockIdx.y * 64;
  const int bn = blockIdx.x * 64;
  const int tid = threadIdx.x;
  const int tx = tid & 15;       // N dir
  const int ty = tid >> 4;       // M dir
  const int lk  = tid & 15;
  const int lm4 = tid >> 4;
  const int ln  = tid & 63;
  const int lkb = tid >> 6;
  float acc[4][4] = {};
  for (int k0 = 0; k0 < K; k0 += 16) {
    #pragma unroll
    for (int i = 0; i < 4; ++i) {
      int m  = lm4 + i * 16;
      int gm = bm + m;
      As[lk][m] = (gm < M) ? A[(long)gm * K + k0 + lk] : 0.f;
    }
    #pragma unroll
    for (int i = 0; i < 4; ++i) {
      int k = lkb * 4 + i;       // 0..15
      Bs[k][ln] = B[(long)(k0 + k) * N + bn + ln];
    }
    __syncthreads();
    #pragma unroll
    for (int kk = 0; kk < 16; ++kk) {
      const float4 av = *(const float4*)&As[kk][ty * 4];
      const float4 bv = *(const float4*)&Bs[kk][tx * 4];
      const float a[4] = {av.x, av.y, av.z, av.w};
      const float b[4] = {bv.x, bv.y, bv.z, bv.w};
      #pragma unroll
      for (int i = 0; i < 4; ++i)
        #pragma unroll
        for (int j = 0; j < 4; ++j)
          acc[i][j] = fmaf(a[i], b[j], acc[i][j]);
    }
    __syncthreads();
  }
  #pragma unroll
  for (int i = 0; i < 4; ++i) {
    int gm = bm + ty * 4 + i;
    if (gm >= M) continue;
    float vv[4];
    #pragma unroll
    for (int j = 0; j < 4; ++j) {
      float t = acc[i][j];
      if (HAS_BIAS) t += bias[bn + tx * 4 + j];
      if (DO_RELU) t = fmaxf(t, 0.f);
      vv[j] = t;
    }
    *(float4*)&C[(long)gm * N + bn + tx * 4] = *(const float4*)vv;
  }
}

// ---------------- GCN aggregation: out[i] = relu( sum_norm + bias ) ----------------
// one block (256 thr) per node; channel per thread; CSR loop is wave-uniform.
__global__ __launch_bounds__(256) void aggregate(
    const float* __restrict__ hw, const int* __restrict__ colidx,
    const int* __restrict__ rowptr, const float* __restrict__ dinv,
    const float* __restrict__ bias, float* __restrict__ out)
{
  const int i = blockIdx.x;
  const int c = threadIdx.x;
  const float di = dinv[i];
  float acc = di * di * hw[(long)i * DC + c];     // self-loop
  const int s0 = rowptr[i], s1 = rowptr[i + 1];
  for (int e = s0; e < s1; ++e) {
    int s = colidx[e];
    acc += di * dinv[s] * hw[(long)s * DC + c];
  }
  out[(long)i * DC + c] = fmaxf(acc + bias[c], 0.f);
}

// ---------------- pool + lin2 + lin3 fused: one block per graph ----------------
__global__ __launch_bounds__(256) void pool_mlp(
    const float* __restrict__ h, const int* __restrict__ batch,
    const float* __restrict__ W2, const float* __restrict__ b2,
    const float* __restrict__ W3, const float* __restrict__ b3,
    float* __restrict__ out)
{
  __shared__ float gmean[DC];
  __shared__ float red[DL];
  const int g = blockIdx.x;
  const int t = threadIdx.x;
  // lower_bound(batch, g) and lower_bound(batch, g+1); batch sorted ascending
  int lo = 0, hi = NN;
  while (lo < hi) { int mid = (lo + hi) >> 1; if (batch[mid] < g) lo = mid + 1; else hi = mid; }
  const int start = lo;
  hi = NN;
  while (lo < hi) { int mid = (lo + hi) >> 1; if (batch[mid] < g + 1) lo = mid + 1; else hi = mid; }
  const int end = lo;
  float s = 0.f;
  for (int i = start; i < end; ++i) s += h[(long)i * DC + t];
  gmean[t] = s / fmaxf((float)(end - start), 1.f);
  __syncthreads();
  if (t < DL) {
    float acc = b2[t];
    for (int k = 0; k < DC; ++k) acc = fmaf(gmean[k], W2[k * DL + t], acc);
    red[t] = fmaxf(acc, 0.f) * W3[t];
  }
  __syncthreads();
  for (int s2 = 64; s2 > 0; s2 >>= 1) {
    if (t < s2) red[t] += red[t + s2];
    __syncthreads();
  }
  if (t == 0) out[g] = red[0] + b3[0];
}

// ---------------- launch ----------------
extern "C" void kernel_launch(void* const* d_in, const int* in_sizes, int n_in,
                              void* d_out, int out_size, void* d_ws, size_t ws_size,
                              hipStream_t stream) {
  const float* x    = (const float*)d_in[0];
  const int*   ei   = (const int*)d_in[1];
  const int*   bat  = (const int*)d_in[2];
  const float* W1   = (const float*)d_in[3];
  const float* b1   = (const float*)d_in[4];
  const float* Wc1  = (const float*)d_in[5];
  const float* bc1  = (const float*)d_in[6];
  const float* Wc2  = (const float*)d_in[7];
  const float* bc2  = (const float*)d_in[8];
  const float* W2   = (const float*)d_in[9];
  const float* b2   = (const float*)d_in[10];
  const float* W3   = (const float*)d_in[11];
  const float* b3   = (const float*)d_in[12];
  float* out = (float*)d_out;

  char* ws = (char*)d_ws;
  float* h1     = (float*)(ws + H1_OFF);
  float* hw     = (float*)(ws + HW_OFF);
  float* h2     = (float*)(ws + H2_OFF);
  float* h3     = (float*)(ws + H1_OFF);   // reuse h1 region
  int*   cnt    = (int*)  (ws + CNT_OFF);
  int*   fill   = (int*)  (ws + FILL_OFF);
  float* dinv   = (float*)(ws + DINV_OFF);
  int*   rowptr = (int*)  (ws + RP_OFF);
  int*   colidx = (int*)  (ws + COL_OFF);

  const int* srcE = ei;
  const int* dstE = ei + NE;

  // zero cnt + fill (adjacent) every call — ws is not re-poisoned between replays
  hipMemsetAsync(cnt, 0, 2 * NN * sizeof(int), stream);

  // graph structure
  count_in<<<(NE + 255) / 256, 256, 0, stream>>>(dstE, cnt);
  compute_dinv<<<(NN + 255) / 256, 256, 0, stream>>>(cnt, dinv);
  scan_rowptr<<<1, 1024, 0, stream>>>(cnt, rowptr);
  fill_csr<<<(NE + 255) / 256, 256, 0, stream>>>(srcE, dstE, rowptr, fill, colidx);

  // lin1: h1 = relu(x @ W1 + b1)   [50000,128]x[128,512]
  {
    dim3 grid(DH / 64, (NN + 63) / 64);
    gemm_f32<1, 1><<<grid, 256, 0, stream>>>(x, W1, b1, h1, NN, DIN, DH);
  }
  // conv1 matmul: hw = h1 @ Wc1    [50000,512]x[512,256]
  {
    dim3 grid(DC / 64, (NN + 63) / 64);
    gemm_f32<0, 0><<<grid, 256, 0, stream>>>(h1, Wc1, nullptr, hw, NN, DH, DC);
  }
  // conv1 aggregate -> h2 (bias + relu)
  aggregate<<<NN, 256, 0, stream>>>(hw, colidx, rowptr, dinv, bc1, h2);
  // conv2 matmul: hw = h2 @ Wc2    [50000,256]x[256,256]
  {
    dim3 grid(DC / 64, (NN + 63) / 64);
    gemm_f32<0, 0><<<grid, 256, 0, stream>>>(h2, Wc2, nullptr, hw, NN, DC, DC);
  }
  // conv2 aggregate -> h3 (bias + relu)
  aggregate<<<NN, 256, 0, stream>>>(hw, colidx, rowptr, dinv, bc2, h3);

  // pool + lin2 + lin3
  pool_mlp<<<NG, 256, 0, stream>>>(h3, bat, W2, b2, W3, b3, out);
}

// Round 2
// 654.922 us; speedup vs baseline: 1.4393x; 1.4393x over previous
//
#include <hip/hip_runtime.h>
#include <hip/hip_bf16.h>

#define NN 50000
#define NE 800000
#define NG 256
#define DIN 128
#define DH 512
#define DC 256   // conv channels
#define DL 128   // lin2 out

// ---------------- workspace layout (bytes) ----------------
#define XBF_OFF   0UL            // 50000*128*2  = 12,800,000
#define H1BF_OFF  12800000UL     // 50000*512*2  = 51,200,000
#define HW_OFF    64000000UL     // 50000*256*4  = 51,200,000
#define H2BF_OFF  115200000UL    // 50000*256*2  = 25,600,000
#define H3_OFF    140800000UL    // 50000*256*4  = 51,200,000
#define W1T_OFF   192000000UL    // 512*128*2    = 131,072
#define WC1T_OFF  192131072UL    // 256*512*2    = 262,144
#define WC2T_OFF  192393216UL    // 256*256*2    = 131,072
#define CNT_OFF   192524288UL    // 50000*4
#define FILL_OFF  192724288UL    // 50000*4 (must directly follow CNT: one memset)
#define DINV_OFF  192924288UL    // 50000*4
#define RP_OFF    193124288UL    // 50001*4
#define COL_OFF   193324544UL    // 800000*4 -> end ~196.5 MB

using bf16x8 = __attribute__((ext_vector_type(8))) short;
using f32x4  = __attribute__((ext_vector_type(4))) float;

__device__ __forceinline__ short f2bf(float f) {
  unsigned u = __builtin_bit_cast(unsigned, f);
  unsigned r = u + 0x7fffu + ((u >> 16) & 1u);   // round-to-nearest-even
  return (short)(r >> 16);
}

// ---------------- graph-structure kernels ----------------
__global__ void count_in(const int* __restrict__ dst, int* __restrict__ cnt) {
  int e = blockIdx.x * blockDim.x + threadIdx.x;
  if (e < NE) atomicAdd(&cnt[dst[e]], 1);
}

__global__ void compute_dinv(const int* __restrict__ cnt, float* __restrict__ dinv) {
  int i = blockIdx.x * blockDim.x + threadIdx.x;
  if (i < NN) dinv[i] = 1.0f / sqrtf((float)(cnt[i] + 1));   // +1 self-loop
}

// single-block exclusive scan of cnt[0..NN) -> rowptr; rowptr[NN] = total
__global__ __launch_bounds__(1024) void scan_rowptr(const int* __restrict__ cnt,
                                                    int* __restrict__ rowptr) {
  __shared__ int wsum[16];
  __shared__ int soff_s;
  const int lane = threadIdx.x & 63, wid = threadIdx.x >> 6;
  if (threadIdx.x == 0) soff_s = 0;
  __syncthreads();
  for (int base = 0; base < NN; base += 1024) {
    int idx = base + threadIdx.x;
    int v = (idx < NN) ? cnt[idx] : 0;
    int incl = v;
    #pragma unroll
    for (int s = 1; s < 64; s <<= 1) {
      int t = __shfl_up(incl, s, 64);
      if (lane >= s) incl += t;
    }
    if (lane == 63) wsum[wid] = incl;
    __syncthreads();
    int woff = 0;
    for (int w = 0; w < wid; ++w) woff += wsum[w];
    int soff = soff_s;
    if (idx < NN) rowptr[idx] = soff + woff + incl - v;
    __syncthreads();
    if (threadIdx.x == 1023) soff_s += woff + incl;  // running total
    __syncthreads();
  }
  if (threadIdx.x == 0) rowptr[NN] = soff_s;
}

__global__ void fill_csr(const int* __restrict__ src, const int* __restrict__ dst,
                         const int* __restrict__ rowptr, int* __restrict__ fill,
                         int* __restrict__ colidx) {
  int e = blockIdx.x * blockDim.x + threadIdx.x;
  if (e < NE) {
    int d = dst[e];
    int pos = rowptr[d] + atomicAdd(&fill[d], 1);
    colidx[pos] = src[e];
  }
}

// ---------------- conversions ----------------
__global__ void cvt_bf16(const float* __restrict__ in, short* __restrict__ out, int n8) {
  int i = blockIdx.x * blockDim.x + threadIdx.x;
  if (i >= n8) return;
  const float4* p = (const float4*)in + (long)i * 2;
  float4 a = p[0], b = p[1];
  bf16x8 o;
  o[0] = f2bf(a.x); o[1] = f2bf(a.y); o[2] = f2bf(a.z); o[3] = f2bf(a.w);
  o[4] = f2bf(b.x); o[5] = f2bf(b.y); o[6] = f2bf(b.z); o[7] = f2bf(b.w);
  *(bf16x8*)(out + (long)i * 8) = o;
}

// out[n*K+k] = bf16(in[k*N+n])   (tiny weight matrices)
__global__ void transpose_bf16(const float* __restrict__ in, short* __restrict__ out,
                               int K, int N) {
  int idx = blockIdx.x * blockDim.x + threadIdx.x;
  if (idx >= K * N) return;
  int n = idx / K, k = idx % K;
  out[idx] = f2bf(in[k * N + n]);
}

// ---------------- bf16 MFMA GEMM: C = relu?(A[M,K] @ Bt[N,K]^T (+bias)) ----------------
// 128x128 tile, 4 waves (2x2), 16x16x32 MFMA, 4x4 fragments/wave.
// LDS tiles padded to stride 40 shorts (80B): ds_read_b128 lands 2-way max.
template<int OUT_BF16, int DO_RELU, int HAS_BIAS>
__global__ __launch_bounds__(256) void gemm_mfma(
    const short* __restrict__ A,   // [M,K] bf16
    const short* __restrict__ Bt,  // [N,K] bf16
    const float* __restrict__ bias,
    void* __restrict__ Cout, int M, int K, int N)
{
  __shared__ __align__(16) short As[128][40];
  __shared__ __align__(16) short Bs[128][40];
  const int tid  = threadIdx.x;
  const int lane = tid & 63;
  const int wave = tid >> 6;       // 0..3
  const int wr   = wave >> 1;      // M dir
  const int wc   = wave & 1;       // N dir
  const int bm = blockIdx.y * 128;
  const int bn = blockIdx.x * 128;

  const int sr  = tid >> 2;        // staging row 0..63
  const int sc8 = (tid & 3) * 8;   // staging col base

  f32x4 acc[4][4];
  #pragma unroll
  for (int m = 0; m < 4; ++m)
    #pragma unroll
    for (int n = 0; n < 4; ++n)
      acc[m][n] = f32x4{0.f, 0.f, 0.f, 0.f};

  const int fr = lane & 15;          // fragment row/col
  const int kb = (lane >> 4) * 8;    // fragment k base

  for (int k0 = 0; k0 < K; k0 += 32) {
    // ---- stage A (with M guard) and Bt (N exact multiple of 128) ----
    #pragma unroll
    for (int h = 0; h < 2; ++h) {
      int r  = sr + h * 64;
      int gm = bm + r;
      int4 av = (gm < M) ? *(const int4*)(A + (long)gm * K + k0 + sc8)
                         : int4{0, 0, 0, 0};
      *(int4*)&As[r][sc8] = av;
      int gn = bn + r;
      *(int4*)&Bs[r][sc8] = *(const int4*)(Bt + (long)gn * K + k0 + sc8);
    }
    __syncthreads();
    // ---- fragments + MFMA ----
    bf16x8 af[4], bf[4];
    #pragma unroll
    for (int m = 0; m < 4; ++m)
      af[m] = *(const bf16x8*)&As[wr * 64 + m * 16 + fr][kb];
    #pragma unroll
    for (int n = 0; n < 4; ++n)
      bf[n] = *(const bf16x8*)&Bs[wc * 64 + n * 16 + fr][kb];
    #pragma unroll
    for (int m = 0; m < 4; ++m)
      #pragma unroll
      for (int n = 0; n < 4; ++n)
        acc[m][n] = __builtin_amdgcn_mfma_f32_16x16x32_bf16(af[m], bf[n], acc[m][n], 0, 0, 0);
    __syncthreads();
  }

  // ---- epilogue: D row = 4*(lane>>4)+r, col = lane&15 ----
  const int cr4 = (lane >> 4) * 4;
  const int cc  = lane & 15;
  #pragma unroll
  for (int m = 0; m < 4; ++m) {
    #pragma unroll
    for (int r = 0; r < 4; ++r) {
      int gm = bm + wr * 64 + m * 16 + cr4 + r;
      if (gm >= M) continue;
      #pragma unroll
      for (int n = 0; n < 4; ++n) {
        int gn = bn + wc * 64 + n * 16 + cc;
        float v = acc[m][n][r];
        if (HAS_BIAS) v += bias[gn];
        if (DO_RELU) v = fmaxf(v, 0.f);
        if (OUT_BF16) ((short*)Cout)[(long)gm * N + gn] = f2bf(v);
        else          ((float*)Cout)[(long)gm * N + gn] = v;
      }
    }
  }
}

// ---------------- GCN aggregation: out[i] = relu( sum_norm + bias ) ----------------
template<int OUT_BF16>
__global__ __launch_bounds__(256) void aggregate(
    const float* __restrict__ hw, const int* __restrict__ colidx,
    const int* __restrict__ rowptr, const float* __restrict__ dinv,
    const float* __restrict__ bias, void* __restrict__ out)
{
  const int i = blockIdx.x;
  const int c = threadIdx.x;
  const float di = dinv[i];
  float acc = di * di * hw[(long)i * DC + c];     // self-loop
  const int s0 = rowptr[i], s1 = rowptr[i + 1];
  for (int e = s0; e < s1; ++e) {
    int s = colidx[e];
    acc += di * dinv[s] * hw[(long)s * DC + c];
  }
  float v = fmaxf(acc + bias[c], 0.f);
  if (OUT_BF16) ((short*)out)[(long)i * DC + c] = f2bf(v);
  else          ((float*)out)[(long)i * DC + c] = v;
}

// ---------------- pool + lin2 + lin3 fused: one block per graph ----------------
__global__ __launch_bounds__(256) void pool_mlp(
    const float* __restrict__ h, const int* __restrict__ batch,
    const float* __restrict__ W2, const float* __restrict__ b2,
    const float* __restrict__ W3, const float* __restrict__ b3,
    float* __restrict__ out)
{
  __shared__ float gmean[DC];
  __shared__ float red[DL];
  const int g = blockIdx.x;
  const int t = threadIdx.x;
  int lo = 0, hi = NN;
  while (lo < hi) { int mid = (lo + hi) >> 1; if (batch[mid] < g) lo = mid + 1; else hi = mid; }
  const int start = lo;
  hi = NN;
  while (lo < hi) { int mid = (lo + hi) >> 1; if (batch[mid] < g + 1) lo = mid + 1; else hi = mid; }
  const int end = lo;
  float s = 0.f;
  for (int i = start; i < end; ++i) s += h[(long)i * DC + t];
  gmean[t] = s / fmaxf((float)(end - start), 1.f);
  __syncthreads();
  if (t < DL) {
    float acc = b2[t];
    for (int k = 0; k < DC; ++k) acc = fmaf(gmean[k], W2[k * DL + t], acc);
    red[t] = fmaxf(acc, 0.f) * W3[t];
  }
  __syncthreads();
  for (int s2 = 64; s2 > 0; s2 >>= 1) {
    if (t < s2) red[t] += red[t + s2];
    __syncthreads();
  }
  if (t == 0) out[g] = red[0] + b3[0];
}

// ---------------- launch ----------------
extern "C" void kernel_launch(void* const* d_in, const int* in_sizes, int n_in,
                              void* d_out, int out_size, void* d_ws, size_t ws_size,
                              hipStream_t stream) {
  const float* x    = (const float*)d_in[0];
  const int*   ei   = (const int*)d_in[1];
  const int*   bat  = (const int*)d_in[2];
  const float* W1   = (const float*)d_in[3];
  const float* b1   = (const float*)d_in[4];
  const float* Wc1  = (const float*)d_in[5];
  const float* bc1  = (const float*)d_in[6];
  const float* Wc2  = (const float*)d_in[7];
  const float* bc2  = (const float*)d_in[8];
  const float* W2   = (const float*)d_in[9];
  const float* b2   = (const float*)d_in[10];
  const float* W3   = (const float*)d_in[11];
  const float* b3   = (const float*)d_in[12];
  float* out = (float*)d_out;

  char* ws = (char*)d_ws;
  short* xbf    = (short*)(ws + XBF_OFF);
  short* h1bf   = (short*)(ws + H1BF_OFF);
  float* hw     = (float*)(ws + HW_OFF);
  short* h2bf   = (short*)(ws + H2BF_OFF);
  float* h3     = (float*)(ws + H3_OFF);
  short* W1t    = (short*)(ws + W1T_OFF);
  short* Wc1t   = (short*)(ws + WC1T_OFF);
  short* Wc2t   = (short*)(ws + WC2T_OFF);
  int*   cnt    = (int*)  (ws + CNT_OFF);
  int*   fill   = (int*)  (ws + FILL_OFF);
  float* dinv   = (float*)(ws + DINV_OFF);
  int*   rowptr = (int*)  (ws + RP_OFF);
  int*   colidx = (int*)  (ws + COL_OFF);

  const int* srcE = ei;
  const int* dstE = ei + NE;

  // zero cnt + fill (adjacent) every call
  hipMemsetAsync(cnt, 0, 2 * NN * sizeof(int), stream);

  // graph structure
  count_in<<<(NE + 255) / 256, 256, 0, stream>>>(dstE, cnt);
  compute_dinv<<<(NN + 255) / 256, 256, 0, stream>>>(cnt, dinv);
  scan_rowptr<<<1, 1024, 0, stream>>>(cnt, rowptr);
  fill_csr<<<(NE + 255) / 256, 256, 0, stream>>>(srcE, dstE, rowptr, fill, colidx);

  // conversions
  cvt_bf16<<<(NN * DIN / 8 + 255) / 256, 256, 0, stream>>>(x, xbf, NN * DIN / 8);
  transpose_bf16<<<(DIN * DH + 255) / 256, 256, 0, stream>>>(W1, W1t, DIN, DH);
  transpose_bf16<<<(DH * DC + 255) / 256, 256, 0, stream>>>(Wc1, Wc1t, DH, DC);
  transpose_bf16<<<(DC * DC + 255) / 256, 256, 0, stream>>>(Wc2, Wc2t, DC, DC);

  // lin1: h1 = relu(x @ W1 + b1) -> bf16
  {
    dim3 grid(DH / 128, (NN + 127) / 128);
    gemm_mfma<1, 1, 1><<<grid, 256, 0, stream>>>(xbf, W1t, b1, h1bf, NN, DIN, DH);
  }
  // conv1 matmul: hw = h1 @ Wc1 -> fp32
  {
    dim3 grid(DC / 128, (NN + 127) / 128);
    gemm_mfma<0, 0, 0><<<grid, 256, 0, stream>>>(h1bf, Wc1t, nullptr, hw, NN, DH, DC);
  }
  // conv1 aggregate -> h2 (bias + relu) -> bf16
  aggregate<1><<<NN, 256, 0, stream>>>(hw, colidx, rowptr, dinv, bc1, h2bf);
  // conv2 matmul: hw = h2 @ Wc2 -> fp32
  {
    dim3 grid(DC / 128, (NN + 127) / 128);
    gemm_mfma<0, 0, 0><<<grid, 256, 0, stream>>>(h2bf, Wc2t, nullptr, hw, NN, DC, DC);
  }
  // conv2 aggregate -> h3 (bias + relu) -> fp32
  aggregate<0><<<NN, 256, 0, stream>>>(hw, colidx, rowptr, dinv, bc2, h3);

  // pool + lin2 + lin3
  pool_mlp<<<NG, 256, 0, stream>>>(h3, bat, W2, b2, W3, b3, out);
}

// Round 3
// 501.422 us; speedup vs baseline: 1.8799x; 1.3061x over previous
//
#include <hip/hip_runtime.h>
#include <hip/hip_bf16.h>

#define NN 50000
#define NE 800000
#define NG 256
#define DIN 128
#define DH 512
#define DC 256   // conv channels
#define DL 128   // lin2 out
#define NB 49    // scan blocks: ceil(50000/1024)

// ---------------- workspace layout (bytes) ----------------
#define XBF_OFF   0UL            // 50000*128*2  = 12,800,000
#define H1BF_OFF  12800000UL     // 50000*512*2  = 51,200,000
#define HWBF_OFF  64000000UL     // 50000*256*2  = 25,600,000
#define H2BF_OFF  89600000UL     // 50000*256*2  = 25,600,000
#define H3_OFF    115200000UL    // 50000*256*4  = 51,200,000
#define W1T_OFF   166400000UL    // 512*128*2    = 131,072
#define WC1T_OFF  166531072UL    // 256*512*2    = 262,144
#define WC2T_OFF  166793216UL    // 256*256*2    = 131,072
#define CNT_OFF   166924288UL    // 50000*4
#define FILL_OFF  167124288UL    // 50000*4 (must directly follow CNT: one memset)
#define DINV_OFF  167324288UL    // 50000*4
#define RP_OFF    167524288UL    // 50001*4 -> ends 167,724,292
#define BSUM_OFF  167724544UL    // 64*4
#define COL_OFF   167724800UL    // 800000*4 -> end ~170.9 MB

using bf16x8 = __attribute__((ext_vector_type(8))) short;
using f32x4  = __attribute__((ext_vector_type(4))) float;

__device__ __forceinline__ short f2bf(float f) {
  unsigned u = __builtin_bit_cast(unsigned, f);
  unsigned r = u + 0x7fffu + ((u >> 16) & 1u);   // round-to-nearest-even
  return (short)(r >> 16);
}
__device__ __forceinline__ float bf2f(unsigned short u) {
  return __builtin_bit_cast(float, (unsigned)u << 16);
}

// ---------------- graph-structure kernels ----------------
__global__ void count_in(const int* __restrict__ dst, int* __restrict__ cnt) {
  int e = blockIdx.x * blockDim.x + threadIdx.x;
  if (e < NE) atomicAdd(&cnt[dst[e]], 1);
}

__global__ void compute_dinv(const int* __restrict__ cnt, float* __restrict__ dinv) {
  int i = blockIdx.x * blockDim.x + threadIdx.x;
  if (i < NN) dinv[i] = 1.0f / sqrtf((float)(cnt[i] + 1));   // +1 self-loop
}

// ---- 3-phase exclusive scan of cnt[0..NN) -> rowptr ----
__global__ __launch_bounds__(1024) void scan_p1(const int* __restrict__ cnt,
                                                int* __restrict__ rowptr,
                                                int* __restrict__ bsum) {
  __shared__ int wsum[16];
  const int idx = blockIdx.x * 1024 + threadIdx.x;
  const int lane = threadIdx.x & 63, wid = threadIdx.x >> 6;
  int v = (idx < NN) ? cnt[idx] : 0;
  int incl = v;
  #pragma unroll
  for (int s = 1; s < 64; s <<= 1) {
    int t = __shfl_up(incl, s, 64);
    if (lane >= s) incl += t;
  }
  if (lane == 63) wsum[wid] = incl;
  __syncthreads();
  if (wid == 0 && lane < 16) {
    int w = wsum[lane];
    int wincl = w;
    #pragma unroll
    for (int s = 1; s < 16; s <<= 1) {
      int t = __shfl_up(wincl, s, 64);
      if (lane >= s) wincl += t;
    }
    wsum[lane] = wincl - w;                 // exclusive wave offset
    if (lane == 15) bsum[blockIdx.x] = wincl;
  }
  __syncthreads();
  if (idx < NN) rowptr[idx] = wsum[wid] + incl - v;
}

__global__ void scan_p2(int* __restrict__ bsum, int* __restrict__ rowptr) {
  const int lane = threadIdx.x;
  int v = (lane < NB) ? bsum[lane] : 0;
  int incl = v;
  #pragma unroll
  for (int s = 1; s < 64; s <<= 1) {
    int t = __shfl_up(incl, s, 64);
    if (lane >= s) incl += t;
  }
  if (lane < NB) bsum[lane] = incl - v;
  if (lane == 63) rowptr[NN] = incl;        // == NE
}

__global__ __launch_bounds__(1024) void scan_p3(int* __restrict__ rowptr,
                                                const int* __restrict__ bsum) {
  const int idx = blockIdx.x * 1024 + threadIdx.x;
  if (idx < NN && blockIdx.x > 0) rowptr[idx] += bsum[blockIdx.x];
}

__global__ void fill_csr(const int* __restrict__ src, const int* __restrict__ dst,
                         const int* __restrict__ rowptr, int* __restrict__ fill,
                         int* __restrict__ colidx) {
  int e = blockIdx.x * blockDim.x + threadIdx.x;
  if (e < NE) {
    int d = dst[e];
    int pos = rowptr[d] + atomicAdd(&fill[d], 1);
    colidx[pos] = src[e];
  }
}

// ---------------- conversions ----------------
__global__ void cvt_bf16(const float* __restrict__ in, short* __restrict__ out, int n8) {
  int i = blockIdx.x * blockDim.x + threadIdx.x;
  if (i >= n8) return;
  const float4* p = (const float4*)in + (long)i * 2;
  float4 a = p[0], b = p[1];
  bf16x8 o;
  o[0] = f2bf(a.x); o[1] = f2bf(a.y); o[2] = f2bf(a.z); o[3] = f2bf(a.w);
  o[4] = f2bf(b.x); o[5] = f2bf(b.y); o[6] = f2bf(b.z); o[7] = f2bf(b.w);
  *(bf16x8*)(out + (long)i * 8) = o;
}

// out[n*K+k] = bf16(in[k*N+n])   (tiny weight matrices)
__global__ void transpose_bf16(const float* __restrict__ in, short* __restrict__ out,
                               int K, int N) {
  int idx = blockIdx.x * blockDim.x + threadIdx.x;
  if (idx >= K * N) return;
  int n = idx / K, k = idx % K;
  out[idx] = f2bf(in[k * N + n]);
}

// ---------------- bf16 MFMA GEMM: C = relu?(A[M,K] @ Bt[N,K]^T (+bias)) ----------------
// 128x128 tile, 4 waves (2x2), 16x16x32 MFMA, 4x4 fragments/wave.
// LDS tiles padded to stride 40 shorts (80B): ds_read_b128 lands 2-way max.
template<int OUT_BF16, int DO_RELU, int HAS_BIAS>
__global__ __launch_bounds__(256) void gemm_mfma(
    const short* __restrict__ A,   // [M,K] bf16
    const short* __restrict__ Bt,  // [N,K] bf16
    const float* __restrict__ bias,
    void* __restrict__ Cout, int M, int K, int N)
{
  __shared__ __align__(16) short As[128][40];
  __shared__ __align__(16) short Bs[128][40];
  const int tid  = threadIdx.x;
  const int lane = tid & 63;
  const int wave = tid >> 6;       // 0..3
  const int wr   = wave >> 1;      // M dir
  const int wc   = wave & 1;       // N dir
  const int bm = blockIdx.y * 128;
  const int bn = blockIdx.x * 128;

  const int sr  = tid >> 2;        // staging row 0..63
  const int sc8 = (tid & 3) * 8;   // staging col base

  f32x4 acc[4][4];
  #pragma unroll
  for (int m = 0; m < 4; ++m)
    #pragma unroll
    for (int n = 0; n < 4; ++n)
      acc[m][n] = f32x4{0.f, 0.f, 0.f, 0.f};

  const int fr = lane & 15;          // fragment row/col
  const int kb = (lane >> 4) * 8;    // fragment k base

  for (int k0 = 0; k0 < K; k0 += 32) {
    #pragma unroll
    for (int h = 0; h < 2; ++h) {
      int r  = sr + h * 64;
      int gm = bm + r;
      int4 av = (gm < M) ? *(const int4*)(A + (long)gm * K + k0 + sc8)
                         : int4{0, 0, 0, 0};
      *(int4*)&As[r][sc8] = av;
      int gn = bn + r;
      *(int4*)&Bs[r][sc8] = *(const int4*)(Bt + (long)gn * K + k0 + sc8);
    }
    __syncthreads();
    bf16x8 af[4], bfr[4];
    #pragma unroll
    for (int m = 0; m < 4; ++m)
      af[m] = *(const bf16x8*)&As[wr * 64 + m * 16 + fr][kb];
    #pragma unroll
    for (int n = 0; n < 4; ++n)
      bfr[n] = *(const bf16x8*)&Bs[wc * 64 + n * 16 + fr][kb];
    #pragma unroll
    for (int m = 0; m < 4; ++m)
      #pragma unroll
      for (int n = 0; n < 4; ++n)
        acc[m][n] = __builtin_amdgcn_mfma_f32_16x16x32_bf16(af[m], bfr[n], acc[m][n], 0, 0, 0);
    __syncthreads();
  }

  const int cr4 = (lane >> 4) * 4;
  const int cc  = lane & 15;
  #pragma unroll
  for (int m = 0; m < 4; ++m) {
    #pragma unroll
    for (int r = 0; r < 4; ++r) {
      int gm = bm + wr * 64 + m * 16 + cr4 + r;
      if (gm >= M) continue;
      #pragma unroll
      for (int n = 0; n < 4; ++n) {
        int gn = bn + wc * 64 + n * 16 + cc;
        float v = acc[m][n][r];
        if (HAS_BIAS) v += bias[gn];
        if (DO_RELU) v = fmaxf(v, 0.f);
        if (OUT_BF16) ((short*)Cout)[(long)gm * N + gn] = f2bf(v);
        else          ((float*)Cout)[(long)gm * N + gn] = v;
      }
    }
  }
}

// ---------------- GCN aggregation (bf16 gather, fp32 accum) ----------------
// 1 wave per node, 4 channels per lane: each neighbor row = 64 lanes x 8B = 512B.
template<int OUT_BF16>
__global__ __launch_bounds__(256) void aggregate_v2(
    const unsigned short* __restrict__ hw, const int* __restrict__ colidx,
    const int* __restrict__ rowptr, const float* __restrict__ dinv,
    const float* __restrict__ bias, void* __restrict__ out)
{
  const int wid  = threadIdx.x >> 6;
  const int lane = threadIdx.x & 63;
  const int i = blockIdx.x * 4 + wid;
  if (i >= NN) return;
  const int c0 = lane * 4;
  const float di = dinv[i];

  ushort4 sv = *(const ushort4*)(hw + (long)i * DC + c0);
  const float dii = di * di;
  float acc0 = dii * bf2f(sv.x);
  float acc1 = dii * bf2f(sv.y);
  float acc2 = dii * bf2f(sv.z);
  float acc3 = dii * bf2f(sv.w);

  const int s0 = rowptr[i], s1 = rowptr[i + 1];
  for (int e = s0; e < s1; ++e) {
    int s = colidx[e];
    float w = di * dinv[s];
    ushort4 v = *(const ushort4*)(hw + (long)s * DC + c0);
    acc0 += w * bf2f(v.x);
    acc1 += w * bf2f(v.y);
    acc2 += w * bf2f(v.z);
    acc3 += w * bf2f(v.w);
  }
  const float4 bv = *(const float4*)(bias + c0);
  acc0 = fmaxf(acc0 + bv.x, 0.f);
  acc1 = fmaxf(acc1 + bv.y, 0.f);
  acc2 = fmaxf(acc2 + bv.z, 0.f);
  acc3 = fmaxf(acc3 + bv.w, 0.f);
  if (OUT_BF16) {
    ushort4 o;
    o.x = (unsigned short)f2bf(acc0); o.y = (unsigned short)f2bf(acc1);
    o.z = (unsigned short)f2bf(acc2); o.w = (unsigned short)f2bf(acc3);
    *(ushort4*)((unsigned short*)out + (long)i * DC + c0) = o;
  } else {
    float4 o = {acc0, acc1, acc2, acc3};
    *(float4*)((float*)out + (long)i * DC + c0) = o;
  }
}

// ---------------- pool + lin2 + lin3 fused: one block per graph ----------------
__global__ __launch_bounds__(256) void pool_mlp(
    const float* __restrict__ h, const int* __restrict__ batch,
    const float* __restrict__ W2, const float* __restrict__ b2,
    const float* __restrict__ W3, const float* __restrict__ b3,
    float* __restrict__ out)
{
  __shared__ float gmean[DC];
  __shared__ float red[DL];
  const int g = blockIdx.x;
  const int t = threadIdx.x;
  int lo = 0, hi = NN;
  while (lo < hi) { int mid = (lo + hi) >> 1; if (batch[mid] < g) lo = mid + 1; else hi = mid; }
  const int start = lo;
  hi = NN;
  while (lo < hi) { int mid = (lo + hi) >> 1; if (batch[mid] < g + 1) lo = mid + 1; else hi = mid; }
  const int end = lo;
  float s = 0.f;
  for (int i = start; i < end; ++i) s += h[(long)i * DC + t];
  gmean[t] = s / fmaxf((float)(end - start), 1.f);
  __syncthreads();
  if (t < DL) {
    float acc = b2[t];
    for (int k = 0; k < DC; ++k) acc = fmaf(gmean[k], W2[k * DL + t], acc);
    red[t] = fmaxf(acc, 0.f) * W3[t];
  }
  __syncthreads();
  for (int s2 = 64; s2 > 0; s2 >>= 1) {
    if (t < s2) red[t] += red[t + s2];
    __syncthreads();
  }
  if (t == 0) out[g] = red[0] + b3[0];
}

// ---------------- launch ----------------
extern "C" void kernel_launch(void* const* d_in, const int* in_sizes, int n_in,
                              void* d_out, int out_size, void* d_ws, size_t ws_size,
                              hipStream_t stream) {
  const float* x    = (const float*)d_in[0];
  const int*   ei   = (const int*)d_in[1];
  const int*   bat  = (const int*)d_in[2];
  const float* W1   = (const float*)d_in[3];
  const float* b1   = (const float*)d_in[4];
  const float* Wc1  = (const float*)d_in[5];
  const float* bc1  = (const float*)d_in[6];
  const float* Wc2  = (const float*)d_in[7];
  const float* bc2  = (const float*)d_in[8];
  const float* W2   = (const float*)d_in[9];
  const float* b2   = (const float*)d_in[10];
  const float* W3   = (const float*)d_in[11];
  const float* b3   = (const float*)d_in[12];
  float* out = (float*)d_out;

  char* ws = (char*)d_ws;
  short* xbf    = (short*)(ws + XBF_OFF);
  short* h1bf   = (short*)(ws + H1BF_OFF);
  unsigned short* hwbf = (unsigned short*)(ws + HWBF_OFF);
  unsigned short* h2bf = (unsigned short*)(ws + H2BF_OFF);
  float* h3     = (float*)(ws + H3_OFF);
  short* W1t    = (short*)(ws + W1T_OFF);
  short* Wc1t   = (short*)(ws + WC1T_OFF);
  short* Wc2t   = (short*)(ws + WC2T_OFF);
  int*   cnt    = (int*)  (ws + CNT_OFF);
  int*   fill   = (int*)  (ws + FILL_OFF);
  float* dinv   = (float*)(ws + DINV_OFF);
  int*   rowptr = (int*)  (ws + RP_OFF);
  int*   bsum   = (int*)  (ws + BSUM_OFF);
  int*   colidx = (int*)  (ws + COL_OFF);

  const int* srcE = ei;
  const int* dstE = ei + NE;

  // zero cnt + fill (adjacent) every call
  hipMemsetAsync(cnt, 0, 2 * NN * sizeof(int), stream);

  // graph structure
  count_in<<<(NE + 255) / 256, 256, 0, stream>>>(dstE, cnt);
  scan_p1<<<NB, 1024, 0, stream>>>(cnt, rowptr, bsum);
  scan_p2<<<1, 64, 0, stream>>>(bsum, rowptr);
  scan_p3<<<NB, 1024, 0, stream>>>(rowptr, bsum);
  compute_dinv<<<(NN + 255) / 256, 256, 0, stream>>>(cnt, dinv);
  fill_csr<<<(NE + 255) / 256, 256, 0, stream>>>(srcE, dstE, rowptr, fill, colidx);

  // conversions
  cvt_bf16<<<(NN * DIN / 8 + 255) / 256, 256, 0, stream>>>(x, xbf, NN * DIN / 8);
  transpose_bf16<<<(DIN * DH + 255) / 256, 256, 0, stream>>>(W1, W1t, DIN, DH);
  transpose_bf16<<<(DH * DC + 255) / 256, 256, 0, stream>>>(Wc1, Wc1t, DH, DC);
  transpose_bf16<<<(DC * DC + 255) / 256, 256, 0, stream>>>(Wc2, Wc2t, DC, DC);

  // lin1: h1 = relu(x @ W1 + b1) -> bf16
  {
    dim3 grid(DH / 128, (NN + 127) / 128);
    gemm_mfma<1, 1, 1><<<grid, 256, 0, stream>>>(xbf, W1t, b1, h1bf, NN, DIN, DH);
  }
  // conv1 matmul: hw = h1 @ Wc1 -> bf16
  {
    dim3 grid(DC / 128, (NN + 127) / 128);
    gemm_mfma<1, 0, 0><<<grid, 256, 0, stream>>>(h1bf, Wc1t, nullptr, (void*)hwbf, NN, DH, DC);
  }
  // conv1 aggregate -> h2 (bias + relu) -> bf16
  aggregate_v2<1><<<(NN + 3) / 4, 256, 0, stream>>>(hwbf, colidx, rowptr, dinv, bc1, h2bf);
  // conv2 matmul: hw = h2 @ Wc2 -> bf16
  {
    dim3 grid(DC / 128, (NN + 127) / 128);
    gemm_mfma<1, 0, 0><<<grid, 256, 0, stream>>>((const short*)h2bf, Wc2t, nullptr, (void*)hwbf, NN, DC, DC);
  }
  // conv2 aggregate -> h3 (bias + relu) -> fp32
  aggregate_v2<0><<<(NN + 3) / 4, 256, 0, stream>>>(hwbf, colidx, rowptr, dinv, bc2, h3);

  // pool + lin2 + lin3
  pool_mlp<<<NG, 256, 0, stream>>>(h3, bat, W2, b2, W3, b3, out);
}

// Round 4
// 382.217 us; speedup vs baseline: 2.4662x; 1.3119x over previous
//
#include <hip/hip_runtime.h>
#include <hip/hip_bf16.h>

#define NN 50000
#define NE 800000
#define NG 256
#define DIN 128
#define DH 512
#define DC 256   // conv channels
#define DL 128   // lin2 out
#define NB 49    // scan blocks: ceil(50000/1024)

// ---------------- workspace layout (bytes) ----------------
#define XBF_OFF   0UL            // 50000*128*2  = 12,800,000
#define H1BF_OFF  12800000UL     // 50000*512*2  = 51,200,000
#define HWBF_OFF  64000000UL     // 50000*256*2  = 25,600,000
#define H2BF_OFF  89600000UL     // 50000*256*2  = 25,600,000
#define H3_OFF    115200000UL    // 50000*256*4  = 51,200,000
#define W1T_OFF   166400000UL    // 512*128*2    = 131,072
#define WC1T_OFF  166531072UL    // 256*512*2    = 262,144
#define WC2T_OFF  166793216UL    // 256*256*2    = 131,072
#define CNT_OFF   166924288UL    // 50000*4
#define FILL_OFF  167124288UL    // 50000*4 (must directly follow CNT: one memset)
#define DINV_OFF  167324288UL    // 50000*4
#define RP_OFF    167524288UL    // 50001*4 -> ends 167,724,292
#define BSUM_OFF  167724544UL    // 64*4
#define COL_OFF   167724800UL    // 800000*4 -> ends 170,924,800
#define EWT_OFF   170924800UL    // 800000*4 -> end ~174.1 MB

using bf16x8 = __attribute__((ext_vector_type(8))) short;
using f32x4  = __attribute__((ext_vector_type(4))) float;

__device__ __forceinline__ short f2bf(float f) {
  unsigned u = __builtin_bit_cast(unsigned, f);
  unsigned r = u + 0x7fffu + ((u >> 16) & 1u);   // round-to-nearest-even
  return (short)(r >> 16);
}
__device__ __forceinline__ float bf2f(unsigned short u) {
  return __builtin_bit_cast(float, (unsigned)u << 16);
}

// ---------------- graph-structure kernels ----------------
__global__ void count_in(const int* __restrict__ dst, int* __restrict__ cnt) {
  int e = blockIdx.x * blockDim.x + threadIdx.x;
  if (e < NE) atomicAdd(&cnt[dst[e]], 1);
}

__global__ void compute_dinv(const int* __restrict__ cnt, float* __restrict__ dinv) {
  int i = blockIdx.x * blockDim.x + threadIdx.x;
  if (i < NN) dinv[i] = 1.0f / sqrtf((float)(cnt[i] + 1));   // +1 self-loop
}

// ---- 3-phase exclusive scan of cnt[0..NN) -> rowptr ----
__global__ __launch_bounds__(1024) void scan_p1(const int* __restrict__ cnt,
                                                int* __restrict__ rowptr,
                                                int* __restrict__ bsum) {
  __shared__ int wsum[16];
  const int idx = blockIdx.x * 1024 + threadIdx.x;
  const int lane = threadIdx.x & 63, wid = threadIdx.x >> 6;
  int v = (idx < NN) ? cnt[idx] : 0;
  int incl = v;
  #pragma unroll
  for (int s = 1; s < 64; s <<= 1) {
    int t = __shfl_up(incl, s, 64);
    if (lane >= s) incl += t;
  }
  if (lane == 63) wsum[wid] = incl;
  __syncthreads();
  if (wid == 0 && lane < 16) {
    int w = wsum[lane];
    int wincl = w;
    #pragma unroll
    for (int s = 1; s < 16; s <<= 1) {
      int t = __shfl_up(wincl, s, 64);
      if (lane >= s) wincl += t;
    }
    wsum[lane] = wincl - w;                 // exclusive wave offset
    if (lane == 15) bsum[blockIdx.x] = wincl;
  }
  __syncthreads();
  if (idx < NN) rowptr[idx] = wsum[wid] + incl - v;
}

__global__ void scan_p2(int* __restrict__ bsum, int* __restrict__ rowptr) {
  const int lane = threadIdx.x;
  int v = (lane < NB) ? bsum[lane] : 0;
  int incl = v;
  #pragma unroll
  for (int s = 1; s < 64; s <<= 1) {
    int t = __shfl_up(incl, s, 64);
    if (lane >= s) incl += t;
  }
  if (lane < NB) bsum[lane] = incl - v;
  if (lane == 63) rowptr[NN] = incl;        // == NE
}

__global__ __launch_bounds__(1024) void scan_p3(int* __restrict__ rowptr,
                                                const int* __restrict__ bsum) {
  const int idx = blockIdx.x * 1024 + threadIdx.x;
  if (idx < NN && blockIdx.x > 0) rowptr[idx] += bsum[blockIdx.x];
}

// fill CSR columns + per-edge normalized weight dinv[dst]*dinv[src]
__global__ void fill_csr(const int* __restrict__ src, const int* __restrict__ dst,
                         const int* __restrict__ rowptr, int* __restrict__ fill,
                         const float* __restrict__ dinv,
                         int* __restrict__ colidx, float* __restrict__ ewt) {
  int e = blockIdx.x * blockDim.x + threadIdx.x;
  if (e < NE) {
    int d = dst[e];
    int s = src[e];
    int pos = rowptr[d] + atomicAdd(&fill[d], 1);
    colidx[pos] = s;
    ewt[pos] = dinv[d] * dinv[s];
  }
}

// ---------------- conversions ----------------
__global__ void cvt_bf16(const float* __restrict__ in, short* __restrict__ out, int n8) {
  int i = blockIdx.x * blockDim.x + threadIdx.x;
  if (i >= n8) return;
  const float4* p = (const float4*)in + (long)i * 2;
  float4 a = p[0], b = p[1];
  bf16x8 o;
  o[0] = f2bf(a.x); o[1] = f2bf(a.y); o[2] = f2bf(a.z); o[3] = f2bf(a.w);
  o[4] = f2bf(b.x); o[5] = f2bf(b.y); o[6] = f2bf(b.z); o[7] = f2bf(b.w);
  *(bf16x8*)(out + (long)i * 8) = o;
}

// out[n*K+k] = bf16(in[k*N+n])   (tiny weight matrices)
__global__ void transpose_bf16(const float* __restrict__ in, short* __restrict__ out,
                               int K, int N) {
  int idx = blockIdx.x * blockDim.x + threadIdx.x;
  if (idx >= K * N) return;
  int n = idx / K, k = idx % K;
  out[idx] = f2bf(in[k * N + n]);
}

// ---------------- bf16 MFMA GEMM: C = relu?(A[M,K] @ Bt[N,K]^T (+bias)) ----------------
// 128x128 tile, 4 waves (2x2), 16x16x32 MFMA, 4x4 fragments/wave.
template<int OUT_BF16, int DO_RELU, int HAS_BIAS>
__global__ __launch_bounds__(256) void gemm_mfma(
    const short* __restrict__ A,   // [M,K] bf16
    const short* __restrict__ Bt,  // [N,K] bf16
    const float* __restrict__ bias,
    void* __restrict__ Cout, int M, int K, int N)
{
  __shared__ __align__(16) short As[128][40];
  __shared__ __align__(16) short Bs[128][40];
  const int tid  = threadIdx.x;
  const int lane = tid & 63;
  const int wave = tid >> 6;       // 0..3
  const int wr   = wave >> 1;      // M dir
  const int wc   = wave & 1;       // N dir
  const int bm = blockIdx.y * 128;
  const int bn = blockIdx.x * 128;

  const int sr  = tid >> 2;        // staging row 0..63
  const int sc8 = (tid & 3) * 8;   // staging col base

  f32x4 acc[4][4];
  #pragma unroll
  for (int m = 0; m < 4; ++m)
    #pragma unroll
    for (int n = 0; n < 4; ++n)
      acc[m][n] = f32x4{0.f, 0.f, 0.f, 0.f};

  const int fr = lane & 15;          // fragment row/col
  const int kb = (lane >> 4) * 8;    // fragment k base

  for (int k0 = 0; k0 < K; k0 += 32) {
    #pragma unroll
    for (int h = 0; h < 2; ++h) {
      int r  = sr + h * 64;
      int gm = bm + r;
      int4 av = (gm < M) ? *(const int4*)(A + (long)gm * K + k0 + sc8)
                         : int4{0, 0, 0, 0};
      *(int4*)&As[r][sc8] = av;
      int gn = bn + r;
      *(int4*)&Bs[r][sc8] = *(const int4*)(Bt + (long)gn * K + k0 + sc8);
    }
    __syncthreads();
    bf16x8 af[4], bfr[4];
    #pragma unroll
    for (int m = 0; m < 4; ++m)
      af[m] = *(const bf16x8*)&As[wr * 64 + m * 16 + fr][kb];
    #pragma unroll
    for (int n = 0; n < 4; ++n)
      bfr[n] = *(const bf16x8*)&Bs[wc * 64 + n * 16 + fr][kb];
    #pragma unroll
    for (int m = 0; m < 4; ++m)
      #pragma unroll
      for (int n = 0; n < 4; ++n)
        acc[m][n] = __builtin_amdgcn_mfma_f32_16x16x32_bf16(af[m], bfr[n], acc[m][n], 0, 0, 0);
    __syncthreads();
  }

  const int cr4 = (lane >> 4) * 4;
  const int cc  = lane & 15;
  #pragma unroll
  for (int m = 0; m < 4; ++m) {
    #pragma unroll
    for (int r = 0; r < 4; ++r) {
      int gm = bm + wr * 64 + m * 16 + cr4 + r;
      if (gm >= M) continue;
      #pragma unroll
      for (int n = 0; n < 4; ++n) {
        int gn = bn + wc * 64 + n * 16 + cc;
        float v = acc[m][n][r];
        if (HAS_BIAS) v += bias[gn];
        if (DO_RELU) v = fmaxf(v, 0.f);
        if (OUT_BF16) ((short*)Cout)[(long)gm * N + gn] = f2bf(v);
        else          ((float*)Cout)[(long)gm * N + gn] = v;
      }
    }
  }
}

// ---------------- GCN aggregation v3 (bf16 gather, precomputed weights, 8x MLP) ----
// 1 wave per node, 4 channels per lane (8B). Edge loop unrolled 8/4/1 with
// statically-indexed arrays so all gathers of a group are in flight together.
template<int OUT_BF16>
__global__ __launch_bounds__(256) void aggregate_v3(
    const unsigned short* __restrict__ hw, const int* __restrict__ colidx,
    const float* __restrict__ ewt, const int* __restrict__ rowptr,
    const float* __restrict__ dinv, const float* __restrict__ bias,
    void* __restrict__ out)
{
  const int wid  = threadIdx.x >> 6;
  const int lane = threadIdx.x & 63;
  const int i = blockIdx.x * 4 + wid;
  if (i >= NN) return;
  const int c0 = lane * 4;
  const float di = dinv[i];

  ushort4 sv = *(const ushort4*)(hw + (long)i * DC + c0);
  const float dii = di * di;
  float acc0 = dii * bf2f(sv.x);
  float acc1 = dii * bf2f(sv.y);
  float acc2 = dii * bf2f(sv.z);
  float acc3 = dii * bf2f(sv.w);

  const int s0 = rowptr[i], s1 = rowptr[i + 1];
  int e = s0;
  for (; e + 8 <= s1; e += 8) {
    int nn[8]; float wv[8]; ushort4 vv[8];
    #pragma unroll
    for (int j = 0; j < 8; ++j) { nn[j] = colidx[e + j]; wv[j] = ewt[e + j]; }
    #pragma unroll
    for (int j = 0; j < 8; ++j) vv[j] = *(const ushort4*)(hw + (long)nn[j] * DC + c0);
    #pragma unroll
    for (int j = 0; j < 8; ++j) {
      acc0 += wv[j] * bf2f(vv[j].x);
      acc1 += wv[j] * bf2f(vv[j].y);
      acc2 += wv[j] * bf2f(vv[j].z);
      acc3 += wv[j] * bf2f(vv[j].w);
    }
  }
  for (; e + 4 <= s1; e += 4) {
    int nn[4]; float wv[4]; ushort4 vv[4];
    #pragma unroll
    for (int j = 0; j < 4; ++j) { nn[j] = colidx[e + j]; wv[j] = ewt[e + j]; }
    #pragma unroll
    for (int j = 0; j < 4; ++j) vv[j] = *(const ushort4*)(hw + (long)nn[j] * DC + c0);
    #pragma unroll
    for (int j = 0; j < 4; ++j) {
      acc0 += wv[j] * bf2f(vv[j].x);
      acc1 += wv[j] * bf2f(vv[j].y);
      acc2 += wv[j] * bf2f(vv[j].z);
      acc3 += wv[j] * bf2f(vv[j].w);
    }
  }
  for (; e < s1; ++e) {
    int s = colidx[e];
    float w = ewt[e];
    ushort4 v = *(const ushort4*)(hw + (long)s * DC + c0);
    acc0 += w * bf2f(v.x);
    acc1 += w * bf2f(v.y);
    acc2 += w * bf2f(v.z);
    acc3 += w * bf2f(v.w);
  }
  const float4 bv = *(const float4*)(bias + c0);
  acc0 = fmaxf(acc0 + bv.x, 0.f);
  acc1 = fmaxf(acc1 + bv.y, 0.f);
  acc2 = fmaxf(acc2 + bv.z, 0.f);
  acc3 = fmaxf(acc3 + bv.w, 0.f);
  if (OUT_BF16) {
    ushort4 o;
    o.x = (unsigned short)f2bf(acc0); o.y = (unsigned short)f2bf(acc1);
    o.z = (unsigned short)f2bf(acc2); o.w = (unsigned short)f2bf(acc3);
    *(ushort4*)((unsigned short*)out + (long)i * DC + c0) = o;
  } else {
    float4 o = {acc0, acc1, acc2, acc3};
    *(float4*)((float*)out + (long)i * DC + c0) = o;
  }
}

// ---------------- pool + lin2 + lin3 fused: one block per graph ----------------
__global__ __launch_bounds__(256) void pool_mlp(
    const float* __restrict__ h, const int* __restrict__ batch,
    const float* __restrict__ W2, const float* __restrict__ b2,
    const float* __restrict__ W3, const float* __restrict__ b3,
    float* __restrict__ out)
{
  __shared__ float gmean[DC];
  __shared__ float red[DL];
  const int g = blockIdx.x;
  const int t = threadIdx.x;
  int lo = 0, hi = NN;
  while (lo < hi) { int mid = (lo + hi) >> 1; if (batch[mid] < g) lo = mid + 1; else hi = mid; }
  const int start = lo;
  hi = NN;
  while (lo < hi) { int mid = (lo + hi) >> 1; if (batch[mid] < g + 1) lo = mid + 1; else hi = mid; }
  const int end = lo;
  float s = 0.f;
  for (int i = start; i < end; ++i) s += h[(long)i * DC + t];
  gmean[t] = s / fmaxf((float)(end - start), 1.f);
  __syncthreads();
  if (t < DL) {
    float acc = b2[t];
    for (int k = 0; k < DC; ++k) acc = fmaf(gmean[k], W2[k * DL + t], acc);
    red[t] = fmaxf(acc, 0.f) * W3[t];
  }
  __syncthreads();
  for (int s2 = 64; s2 > 0; s2 >>= 1) {
    if (t < s2) red[t] += red[t + s2];
    __syncthreads();
  }
  if (t == 0) out[g] = red[0] + b3[0];
}

// ---------------- launch ----------------
extern "C" void kernel_launch(void* const* d_in, const int* in_sizes, int n_in,
                              void* d_out, int out_size, void* d_ws, size_t ws_size,
                              hipStream_t stream) {
  const float* x    = (const float*)d_in[0];
  const int*   ei   = (const int*)d_in[1];
  const int*   bat  = (const int*)d_in[2];
  const float* W1   = (const float*)d_in[3];
  const float* b1   = (const float*)d_in[4];
  const float* Wc1  = (const float*)d_in[5];
  const float* bc1  = (const float*)d_in[6];
  const float* Wc2  = (const float*)d_in[7];
  const float* bc2  = (const float*)d_in[8];
  const float* W2   = (const float*)d_in[9];
  const float* b2   = (const float*)d_in[10];
  const float* W3   = (const float*)d_in[11];
  const float* b3   = (const float*)d_in[12];
  float* out = (float*)d_out;

  char* ws = (char*)d_ws;
  short* xbf    = (short*)(ws + XBF_OFF);
  short* h1bf   = (short*)(ws + H1BF_OFF);
  unsigned short* hwbf = (unsigned short*)(ws + HWBF_OFF);
  unsigned short* h2bf = (unsigned short*)(ws + H2BF_OFF);
  float* h3     = (float*)(ws + H3_OFF);
  short* W1t    = (short*)(ws + W1T_OFF);
  short* Wc1t   = (short*)(ws + WC1T_OFF);
  short* Wc2t   = (short*)(ws + WC2T_OFF);
  int*   cnt    = (int*)  (ws + CNT_OFF);
  int*   fill   = (int*)  (ws + FILL_OFF);
  float* dinv   = (float*)(ws + DINV_OFF);
  int*   rowptr = (int*)  (ws + RP_OFF);
  int*   bsum   = (int*)  (ws + BSUM_OFF);
  int*   colidx = (int*)  (ws + COL_OFF);
  float* ewt    = (float*)(ws + EWT_OFF);

  const int* srcE = ei;
  const int* dstE = ei + NE;

  // zero cnt + fill (adjacent) every call
  hipMemsetAsync(cnt, 0, 2 * NN * sizeof(int), stream);

  // graph structure
  count_in<<<(NE + 255) / 256, 256, 0, stream>>>(dstE, cnt);
  scan_p1<<<NB, 1024, 0, stream>>>(cnt, rowptr, bsum);
  scan_p2<<<1, 64, 0, stream>>>(bsum, rowptr);
  scan_p3<<<NB, 1024, 0, stream>>>(rowptr, bsum);
  compute_dinv<<<(NN + 255) / 256, 256, 0, stream>>>(cnt, dinv);
  fill_csr<<<(NE + 255) / 256, 256, 0, stream>>>(srcE, dstE, rowptr, fill, dinv, colidx, ewt);

  // conversions
  cvt_bf16<<<(NN * DIN / 8 + 255) / 256, 256, 0, stream>>>(x, xbf, NN * DIN / 8);
  transpose_bf16<<<(DIN * DH + 255) / 256, 256, 0, stream>>>(W1, W1t, DIN, DH);
  transpose_bf16<<<(DH * DC + 255) / 256, 256, 0, stream>>>(Wc1, Wc1t, DH, DC);
  transpose_bf16<<<(DC * DC + 255) / 256, 256, 0, stream>>>(Wc2, Wc2t, DC, DC);

  // lin1: h1 = relu(x @ W1 + b1) -> bf16
  {
    dim3 grid(DH / 128, (NN + 127) / 128);
    gemm_mfma<1, 1, 1><<<grid, 256, 0, stream>>>(xbf, W1t, b1, h1bf, NN, DIN, DH);
  }
  // conv1 matmul: hw = h1 @ Wc1 -> bf16
  {
    dim3 grid(DC / 128, (NN + 127) / 128);
    gemm_mfma<1, 0, 0><<<grid, 256, 0, stream>>>(h1bf, Wc1t, nullptr, (void*)hwbf, NN, DH, DC);
  }
  // conv1 aggregate -> h2 (bias + relu) -> bf16
  aggregate_v3<1><<<(NN + 3) / 4, 256, 0, stream>>>(hwbf, colidx, ewt, rowptr, dinv, bc1, h2bf);
  // conv2 matmul: hw = h2 @ Wc2 -> bf16
  {
    dim3 grid(DC / 128, (NN + 127) / 128);
    gemm_mfma<1, 0, 0><<<grid, 256, 0, stream>>>((const short*)h2bf, Wc2t, nullptr, (void*)hwbf, NN, DC, DC);
  }
  // conv2 aggregate -> h3 (bias + relu) -> fp32
  aggregate_v3<0><<<(NN + 3) / 4, 256, 0, stream>>>(hwbf, colidx, ewt, rowptr, dinv, bc2, h3);

  // pool + lin2 + lin3
  pool_mlp<<<NG, 256, 0, stream>>>(h3, bat, W2, b2, W3, b3, out);
}

// Round 5
// 346.142 us; speedup vs baseline: 2.7232x; 1.1042x over previous
//
#include <hip/hip_runtime.h>
#include <hip/hip_bf16.h>

#define NN 50000
#define NE 800000
#define NG 256
#define DIN 128
#define DH 512
#define DC 256   // conv channels
#define DL 128   // lin2 out
#define NB 49    // scan blocks: ceil(50000/1024)

// ---------------- workspace layout (bytes) ----------------
#define XBF_OFF   0UL            // 50000*128*2  = 12,800,000
#define H1BF_OFF  12800000UL     // 50000*512*2  = 51,200,000
#define HWBF_OFF  64000000UL     // 50000*256*2  = 25,600,000
#define H2BF_OFF  89600000UL     // 50000*256*2  = 25,600,000
#define H3_OFF    115200000UL    // 50000*256*4  = 51,200,000
#define W1T_OFF   166400000UL    // 512*128*2    = 131,072
#define WC1T_OFF  166531072UL    // 256*512*2    = 262,144
#define WC2T_OFF  166793216UL    // 256*256*2    = 131,072
#define CNT_OFF   166924288UL    // 50000*4
#define FILL_OFF  167124288UL    // 50000*4 (must directly follow CNT: one memset)
#define DINV_OFF  167324288UL    // 50000*4
#define RP_OFF    167524288UL    // 50001*4 -> ends 167,724,292
#define BSUM_OFF  167724544UL    // 64*4
#define COL_OFF   167724800UL    // 800000*4 -> ends 170,924,800
#define EWT_OFF   170924800UL    // 800000*4 -> end ~174.1 MB

using bf16x8 = __attribute__((ext_vector_type(8))) short;
using f32x4  = __attribute__((ext_vector_type(4))) float;

__device__ __forceinline__ short f2bf(float f) {
  unsigned u = __builtin_bit_cast(unsigned, f);
  unsigned r = u + 0x7fffu + ((u >> 16) & 1u);   // round-to-nearest-even
  return (short)(r >> 16);
}
__device__ __forceinline__ float bf2f(unsigned short u) {
  return __builtin_bit_cast(float, (unsigned)u << 16);
}

// ---------------- graph-structure kernels ----------------
__global__ void count_in(const int* __restrict__ dst, int* __restrict__ cnt) {
  int e = blockIdx.x * blockDim.x + threadIdx.x;
  if (e < NE) atomicAdd(&cnt[dst[e]], 1);
}

__global__ void compute_dinv(const int* __restrict__ cnt, float* __restrict__ dinv) {
  int i = blockIdx.x * blockDim.x + threadIdx.x;
  if (i < NN) dinv[i] = 1.0f / sqrtf((float)(cnt[i] + 1));   // +1 self-loop
}

// ---- 3-phase exclusive scan of cnt[0..NN) -> rowptr ----
__global__ __launch_bounds__(1024) void scan_p1(const int* __restrict__ cnt,
                                                int* __restrict__ rowptr,
                                                int* __restrict__ bsum) {
  __shared__ int wsum[16];
  const int idx = blockIdx.x * 1024 + threadIdx.x;
  const int lane = threadIdx.x & 63, wid = threadIdx.x >> 6;
  int v = (idx < NN) ? cnt[idx] : 0;
  int incl = v;
  #pragma unroll
  for (int s = 1; s < 64; s <<= 1) {
    int t = __shfl_up(incl, s, 64);
    if (lane >= s) incl += t;
  }
  if (lane == 63) wsum[wid] = incl;
  __syncthreads();
  if (wid == 0 && lane < 16) {
    int w = wsum[lane];
    int wincl = w;
    #pragma unroll
    for (int s = 1; s < 16; s <<= 1) {
      int t = __shfl_up(wincl, s, 64);
      if (lane >= s) wincl += t;
    }
    wsum[lane] = wincl - w;                 // exclusive wave offset
    if (lane == 15) bsum[blockIdx.x] = wincl;
  }
  __syncthreads();
  if (idx < NN) rowptr[idx] = wsum[wid] + incl - v;
}

__global__ void scan_p2(int* __restrict__ bsum, int* __restrict__ rowptr) {
  const int lane = threadIdx.x;
  int v = (lane < NB) ? bsum[lane] : 0;
  int incl = v;
  #pragma unroll
  for (int s = 1; s < 64; s <<= 1) {
    int t = __shfl_up(incl, s, 64);
    if (lane >= s) incl += t;
  }
  if (lane < NB) bsum[lane] = incl - v;
  if (lane == 63) rowptr[NN] = incl;        // == NE
}

__global__ __launch_bounds__(1024) void scan_p3(int* __restrict__ rowptr,
                                                const int* __restrict__ bsum) {
  const int idx = blockIdx.x * 1024 + threadIdx.x;
  if (idx < NN && blockIdx.x > 0) rowptr[idx] += bsum[blockIdx.x];
}

// fill CSR columns + per-edge normalized weight dinv[dst]*dinv[src]
__global__ void fill_csr(const int* __restrict__ src, const int* __restrict__ dst,
                         const int* __restrict__ rowptr, int* __restrict__ fill,
                         const float* __restrict__ dinv,
                         int* __restrict__ colidx, float* __restrict__ ewt) {
  int e = blockIdx.x * blockDim.x + threadIdx.x;
  if (e < NE) {
    int d = dst[e];
    int s = src[e];
    int pos = rowptr[d] + atomicAdd(&fill[d], 1);
    colidx[pos] = s;
    ewt[pos] = dinv[d] * dinv[s];
  }
}

// ---------------- conversions ----------------
__global__ void cvt_bf16(const float* __restrict__ in, short* __restrict__ out, int n8) {
  int i = blockIdx.x * blockDim.x + threadIdx.x;
  if (i >= n8) return;
  const float4* p = (const float4*)in + (long)i * 2;
  float4 a = p[0], b = p[1];
  bf16x8 o;
  o[0] = f2bf(a.x); o[1] = f2bf(a.y); o[2] = f2bf(a.z); o[3] = f2bf(a.w);
  o[4] = f2bf(b.x); o[5] = f2bf(b.y); o[6] = f2bf(b.z); o[7] = f2bf(b.w);
  *(bf16x8*)(out + (long)i * 8) = o;
}

// out[n*K+k] = bf16(in[k*N+n])   (tiny weight matrices)
__global__ void transpose_bf16(const float* __restrict__ in, short* __restrict__ out,
                               int K, int N) {
  int idx = blockIdx.x * blockDim.x + threadIdx.x;
  if (idx >= K * N) return;
  int n = idx / K, k = idx % K;
  out[idx] = f2bf(in[k * N + n]);
}

// ---------------- bf16 MFMA GEMM: C = relu?(A[M,K] @ Bt[N,K]^T (+bias)) ----------------
// 128x128 tile, 4 waves (2x2), 16x16x32 MFMA, 4x4 fragments/wave.
template<int OUT_BF16, int DO_RELU, int HAS_BIAS>
__global__ __launch_bounds__(256) void gemm_mfma(
    const short* __restrict__ A,   // [M,K] bf16
    const short* __restrict__ Bt,  // [N,K] bf16
    const float* __restrict__ bias,
    void* __restrict__ Cout, int M, int K, int N)
{
  __shared__ __align__(16) short As[128][40];
  __shared__ __align__(16) short Bs[128][40];
  const int tid  = threadIdx.x;
  const int lane = tid & 63;
  const int wave = tid >> 6;       // 0..3
  const int wr   = wave >> 1;      // M dir
  const int wc   = wave & 1;       // N dir
  const int bm = blockIdx.y * 128;
  const int bn = blockIdx.x * 128;

  const int sr  = tid >> 2;        // staging row 0..63
  const int sc8 = (tid & 3) * 8;   // staging col base

  f32x4 acc[4][4];
  #pragma unroll
  for (int m = 0; m < 4; ++m)
    #pragma unroll
    for (int n = 0; n < 4; ++n)
      acc[m][n] = f32x4{0.f, 0.f, 0.f, 0.f};

  const int fr = lane & 15;          // fragment row/col
  const int kb = (lane >> 4) * 8;    // fragment k base

  for (int k0 = 0; k0 < K; k0 += 32) {
    #pragma unroll
    for (int h = 0; h < 2; ++h) {
      int r  = sr + h * 64;
      int gm = bm + r;
      int4 av = (gm < M) ? *(const int4*)(A + (long)gm * K + k0 + sc8)
                         : int4{0, 0, 0, 0};
      *(int4*)&As[r][sc8] = av;
      int gn = bn + r;
      *(int4*)&Bs[r][sc8] = *(const int4*)(Bt + (long)gn * K + k0 + sc8);
    }
    __syncthreads();
    bf16x8 af[4], bfr[4];
    #pragma unroll
    for (int m = 0; m < 4; ++m)
      af[m] = *(const bf16x8*)&As[wr * 64 + m * 16 + fr][kb];
    #pragma unroll
    for (int n = 0; n < 4; ++n)
      bfr[n] = *(const bf16x8*)&Bs[wc * 64 + n * 16 + fr][kb];
    #pragma unroll
    for (int m = 0; m < 4; ++m)
      #pragma unroll
      for (int n = 0; n < 4; ++n)
        acc[m][n] = __builtin_amdgcn_mfma_f32_16x16x32_bf16(af[m], bfr[n], acc[m][n], 0, 0, 0);
    __syncthreads();
  }

  const int cr4 = (lane >> 4) * 4;
  const int cc  = lane & 15;
  #pragma unroll
  for (int m = 0; m < 4; ++m) {
    #pragma unroll
    for (int r = 0; r < 4; ++r) {
      int gm = bm + wr * 64 + m * 16 + cr4 + r;
      if (gm >= M) continue;
      #pragma unroll
      for (int n = 0; n < 4; ++n) {
        int gn = bn + wc * 64 + n * 16 + cc;
        float v = acc[m][n][r];
        if (HAS_BIAS) v += bias[gn];
        if (DO_RELU) v = fmaxf(v, 0.f);
        if (OUT_BF16) ((short*)Cout)[(long)gm * N + gn] = f2bf(v);
        else          ((float*)Cout)[(long)gm * N + gn] = v;
      }
    }
  }
}

// ---------------- GCN aggregation v3 (bf16 gather, precomputed weights, 8x MLP) ----
template<int OUT_BF16>
__global__ __launch_bounds__(256) void aggregate_v3(
    const unsigned short* __restrict__ hw, const int* __restrict__ colidx,
    const float* __restrict__ ewt, const int* __restrict__ rowptr,
    const float* __restrict__ dinv, const float* __restrict__ bias,
    void* __restrict__ out)
{
  const int wid  = threadIdx.x >> 6;
  const int lane = threadIdx.x & 63;
  const int i = blockIdx.x * 4 + wid;
  if (i >= NN) return;
  const int c0 = lane * 4;
  const float di = dinv[i];

  ushort4 sv = *(const ushort4*)(hw + (long)i * DC + c0);
  const float dii = di * di;
  float acc0 = dii * bf2f(sv.x);
  float acc1 = dii * bf2f(sv.y);
  float acc2 = dii * bf2f(sv.z);
  float acc3 = dii * bf2f(sv.w);

  const int s0 = rowptr[i], s1 = rowptr[i + 1];
  int e = s0;
  for (; e + 8 <= s1; e += 8) {
    int nn[8]; float wv[8]; ushort4 vv[8];
    #pragma unroll
    for (int j = 0; j < 8; ++j) { nn[j] = colidx[e + j]; wv[j] = ewt[e + j]; }
    #pragma unroll
    for (int j = 0; j < 8; ++j) vv[j] = *(const ushort4*)(hw + (long)nn[j] * DC + c0);
    #pragma unroll
    for (int j = 0; j < 8; ++j) {
      acc0 += wv[j] * bf2f(vv[j].x);
      acc1 += wv[j] * bf2f(vv[j].y);
      acc2 += wv[j] * bf2f(vv[j].z);
      acc3 += wv[j] * bf2f(vv[j].w);
    }
  }
  for (; e + 4 <= s1; e += 4) {
    int nn[4]; float wv[4]; ushort4 vv[4];
    #pragma unroll
    for (int j = 0; j < 4; ++j) { nn[j] = colidx[e + j]; wv[j] = ewt[e + j]; }
    #pragma unroll
    for (int j = 0; j < 4; ++j) vv[j] = *(const ushort4*)(hw + (long)nn[j] * DC + c0);
    #pragma unroll
    for (int j = 0; j < 4; ++j) {
      acc0 += wv[j] * bf2f(vv[j].x);
      acc1 += wv[j] * bf2f(vv[j].y);
      acc2 += wv[j] * bf2f(vv[j].z);
      acc3 += wv[j] * bf2f(vv[j].w);
    }
  }
  for (; e < s1; ++e) {
    int s = colidx[e];
    float w = ewt[e];
    ushort4 v = *(const ushort4*)(hw + (long)s * DC + c0);
    acc0 += w * bf2f(v.x);
    acc1 += w * bf2f(v.y);
    acc2 += w * bf2f(v.z);
    acc3 += w * bf2f(v.w);
  }
  const float4 bv = *(const float4*)(bias + c0);
  acc0 = fmaxf(acc0 + bv.x, 0.f);
  acc1 = fmaxf(acc1 + bv.y, 0.f);
  acc2 = fmaxf(acc2 + bv.z, 0.f);
  acc3 = fmaxf(acc3 + bv.w, 0.f);
  if (OUT_BF16) {
    ushort4 o;
    o.x = (unsigned short)f2bf(acc0); o.y = (unsigned short)f2bf(acc1);
    o.z = (unsigned short)f2bf(acc2); o.w = (unsigned short)f2bf(acc3);
    *(ushort4*)((unsigned short*)out + (long)i * DC + c0) = o;
  } else {
    float4 o = {acc0, acc1, acc2, acc3};
    *(float4*)((float*)out + (long)i * DC + c0) = o;
  }
}

// ---------------- pool + lin2 + lin3 fused v2: one block per graph ----------------
// 256 thr = 4 row-groups x 64 lanes; lane holds 4 channels (float4).
// Node loop strided by 4, unrolled x2 (two independent accumulators)
// -> 8 rows in flight per block instead of 1 (was latency-bound serial chain).
__global__ __launch_bounds__(256) void pool_mlp_v2(
    const float* __restrict__ h, const int* __restrict__ batch,
    const float* __restrict__ W2, const float* __restrict__ b2,
    const float* __restrict__ W3, const float* __restrict__ b3,
    float* __restrict__ out)
{
  __shared__ float part[4][DC];   // 4 KB
  __shared__ float gmean[DC];
  __shared__ float red[DL];
  const int g = blockIdx.x;
  const int t = threadIdx.x;
  const int wid = t >> 6;
  const int lane = t & 63;
  const int c0 = lane * 4;

  // segment bounds: lower_bound(batch,g), lower_bound(batch,g+1)
  int lo = 0, hi = NN;
  while (lo < hi) { int mid = (lo + hi) >> 1; if (batch[mid] < g) lo = mid + 1; else hi = mid; }
  const int start = lo;
  hi = NN;
  while (lo < hi) { int mid = (lo + hi) >> 1; if (batch[mid] < g + 1) lo = mid + 1; else hi = mid; }
  const int end = lo;

  float4 a0 = {0.f, 0.f, 0.f, 0.f}, a1 = {0.f, 0.f, 0.f, 0.f};
  int i = start + wid;
  for (; i + 4 < end; i += 8) {
    float4 v0 = *(const float4*)(h + (long)i * DC + c0);
    float4 v1 = *(const float4*)(h + (long)(i + 4) * DC + c0);
    a0.x += v0.x; a0.y += v0.y; a0.z += v0.z; a0.w += v0.w;
    a1.x += v1.x; a1.y += v1.y; a1.z += v1.z; a1.w += v1.w;
  }
  if (i < end) {
    float4 v0 = *(const float4*)(h + (long)i * DC + c0);
    a0.x += v0.x; a0.y += v0.y; a0.z += v0.z; a0.w += v0.w;
  }
  a0.x += a1.x; a0.y += a1.y; a0.z += a1.z; a0.w += a1.w;
  *(float4*)&part[wid][c0] = a0;
  __syncthreads();
  if (wid == 0) {
    const float inv = 1.0f / fmaxf((float)(end - start), 1.f);
    float4 s0 = *(const float4*)&part[0][c0];
    float4 s1 = *(const float4*)&part[1][c0];
    float4 s2 = *(const float4*)&part[2][c0];
    float4 s3 = *(const float4*)&part[3][c0];
    float4 m;
    m.x = (s0.x + s1.x + s2.x + s3.x) * inv;
    m.y = (s0.y + s1.y + s2.y + s3.y) * inv;
    m.z = (s0.z + s1.z + s2.z + s3.z) * inv;
    m.w = (s0.w + s1.w + s2.w + s3.w) * inv;
    *(float4*)&gmean[c0] = m;
  }
  __syncthreads();
  if (t < DL) {
    float acc = b2[t];
    for (int k = 0; k < DC; ++k) acc = fmaf(gmean[k], W2[k * DL + t], acc);
    red[t] = fmaxf(acc, 0.f) * W3[t];
  }
  __syncthreads();
  for (int s2 = 64; s2 > 0; s2 >>= 1) {
    if (t < s2) red[t] += red[t + s2];
    __syncthreads();
  }
  if (t == 0) out[g] = red[0] + b3[0];
}

// ---------------- launch ----------------
extern "C" void kernel_launch(void* const* d_in, const int* in_sizes, int n_in,
                              void* d_out, int out_size, void* d_ws, size_t ws_size,
                              hipStream_t stream) {
  const float* x    = (const float*)d_in[0];
  const int*   ei   = (const int*)d_in[1];
  const int*   bat  = (const int*)d_in[2];
  const float* W1   = (const float*)d_in[3];
  const float* b1   = (const float*)d_in[4];
  const float* Wc1  = (const float*)d_in[5];
  const float* bc1  = (const float*)d_in[6];
  const float* Wc2  = (const float*)d_in[7];
  const float* bc2  = (const float*)d_in[8];
  const float* W2   = (const float*)d_in[9];
  const float* b2   = (const float*)d_in[10];
  const float* W3   = (const float*)d_in[11];
  const float* b3   = (const float*)d_in[12];
  float* out = (float*)d_out;

  char* ws = (char*)d_ws;
  short* xbf    = (short*)(ws + XBF_OFF);
  short* h1bf   = (short*)(ws + H1BF_OFF);
  unsigned short* hwbf = (unsigned short*)(ws + HWBF_OFF);
  unsigned short* h2bf = (unsigned short*)(ws + H2BF_OFF);
  float* h3     = (float*)(ws + H3_OFF);
  short* W1t    = (short*)(ws + W1T_OFF);
  short* Wc1t   = (short*)(ws + WC1T_OFF);
  short* Wc2t   = (short*)(ws + WC2T_OFF);
  int*   cnt    = (int*)  (ws + CNT_OFF);
  int*   fill   = (int*)  (ws + FILL_OFF);
  float* dinv   = (float*)(ws + DINV_OFF);
  int*   rowptr = (int*)  (ws + RP_OFF);
  int*   bsum   = (int*)  (ws + BSUM_OFF);
  int*   colidx = (int*)  (ws + COL_OFF);
  float* ewt    = (float*)(ws + EWT_OFF);

  const int* srcE = ei;
  const int* dstE = ei + NE;

  // zero cnt + fill (adjacent) every call
  hipMemsetAsync(cnt, 0, 2 * NN * sizeof(int), stream);

  // graph structure
  count_in<<<(NE + 255) / 256, 256, 0, stream>>>(dstE, cnt);
  scan_p1<<<NB, 1024, 0, stream>>>(cnt, rowptr, bsum);
  scan_p2<<<1, 64, 0, stream>>>(bsum, rowptr);
  scan_p3<<<NB, 1024, 0, stream>>>(rowptr, bsum);
  compute_dinv<<<(NN + 255) / 256, 256, 0, stream>>>(cnt, dinv);
  fill_csr<<<(NE + 255) / 256, 256, 0, stream>>>(srcE, dstE, rowptr, fill, dinv, colidx, ewt);

  // conversions
  cvt_bf16<<<(NN * DIN / 8 + 255) / 256, 256, 0, stream>>>(x, xbf, NN * DIN / 8);
  transpose_bf16<<<(DIN * DH + 255) / 256, 256, 0, stream>>>(W1, W1t, DIN, DH);
  transpose_bf16<<<(DH * DC + 255) / 256, 256, 0, stream>>>(Wc1, Wc1t, DH, DC);
  transpose_bf16<<<(DC * DC + 255) / 256, 256, 0, stream>>>(Wc2, Wc2t, DC, DC);

  // lin1: h1 = relu(x @ W1 + b1) -> bf16
  {
    dim3 grid(DH / 128, (NN + 127) / 128);
    gemm_mfma<1, 1, 1><<<grid, 256, 0, stream>>>(xbf, W1t, b1, h1bf, NN, DIN, DH);
  }
  // conv1 matmul: hw = h1 @ Wc1 -> bf16
  {
    dim3 grid(DC / 128, (NN + 127) / 128);
    gemm_mfma<1, 0, 0><<<grid, 256, 0, stream>>>(h1bf, Wc1t, nullptr, (void*)hwbf, NN, DH, DC);
  }
  // conv1 aggregate -> h2 (bias + relu) -> bf16
  aggregate_v3<1><<<(NN + 3) / 4, 256, 0, stream>>>(hwbf, colidx, ewt, rowptr, dinv, bc1, h2bf);
  // conv2 matmul: hw = h2 @ Wc2 -> bf16
  {
    dim3 grid(DC / 128, (NN + 127) / 128);
    gemm_mfma<1, 0, 0><<<grid, 256, 0, stream>>>((const short*)h2bf, Wc2t, nullptr, (void*)hwbf, NN, DC, DC);
  }
  // conv2 aggregate -> h3 (bias + relu) -> fp32
  aggregate_v3<0><<<(NN + 3) / 4, 256, 0, stream>>>(hwbf, colidx, ewt, rowptr, dinv, bc2, h3);

  // pool + lin2 + lin3
  pool_mlp_v2<<<NG, 256, 0, stream>>>(h3, bat, W2, b2, W3, b3, out);
}